// Round 2
// 440.148 us; speedup vs baseline: 1.0472x; 1.0472x over previous
//
#include <hip/hip_runtime.h>
#include <stdint.h>

// ---------- types / helpers ----------
typedef __attribute__((ext_vector_type(8))) short bf16x8;   // 8 x bf16 (4 VGPRs)
typedef __attribute__((ext_vector_type(4))) float f32x4;

__device__ __forceinline__ float bf2f(ushort u) {
  union { uint32_t u; float f; } v; v.u = ((uint32_t)u) << 16; return v.f;
}
__device__ __forceinline__ ushort f2bf(float f) {
  union { float f; uint32_t u; } v; v.f = f;
  uint32_t r = (v.u + 0x7fffu + ((v.u >> 16) & 1u)) >> 16;   // RNE
  return (ushort)r;
}

__device__ __forceinline__ f32x4 mfma16(bf16x8 a, bf16x8 b, f32x4 c) {
  return __builtin_amdgcn_mfma_f32_16x16x32_bf16(a, b, c, 0, 0, 0);
}

// async global->LDS, 16B per lane; LDS dest = wave-uniform base + lane*16
__device__ __forceinline__ void glds16(const ushort* g, ushort* l) {
  __builtin_amdgcn_global_load_lds(
      (__attribute__((address_space(1))) void*)(void*)g,
      (__attribute__((address_space(3))) void*)(void*)l, 16, 0, 0);
}

#define BAR()  __builtin_amdgcn_s_barrier()
#define LGK0() asm volatile("s_waitcnt lgkmcnt(0)" ::: "memory")
#define VMC4() asm volatile("s_waitcnt vmcnt(4)" ::: "memory")
#define VMC0() asm volatile("s_waitcnt vmcnt(0)" ::: "memory")
#define PRIO1() __builtin_amdgcn_s_setprio(1)
#define PRIO0() __builtin_amdgcn_s_setprio(0)

// ---------- elementwise cast fp32 -> bf16 (vectorized x4) ----------
__global__ __launch_bounds__(256) void cast_f32_bf16(
    const float* __restrict__ in, ushort* __restrict__ out, long n) {
  const long i = ((long)blockIdx.x * 256 + threadIdx.x) * 4;
  if (i + 3 >= n) {
    for (long j = i; j < n; j++) out[j] = f2bf(in[j]);
    return;
  }
  const float4 v = *(const float4*)&in[i];
  ushort4 o;
  o.x = f2bf(v.x); o.y = f2bf(v.y); o.z = f2bf(v.z); o.w = f2bf(v.w);
  *(ushort4*)&out[i] = o;
}

// ---------- weight transpose+cast: in fp32 [R][C] -> out bf16 [C][R] ----------
__global__ __launch_bounds__(256) void transpose_cast(
    const float* __restrict__ in, ushort* __restrict__ out, int R, int C) {
  __shared__ ushort t[32][33];
  const int tx = threadIdx.x & 31, ty = threadIdx.x >> 5;  // 32 x 8
  const int bc = blockIdx.x * 32;
  const int br = blockIdx.y * 32;
#pragma unroll
  for (int i = 0; i < 32; i += 8)
    t[ty + i][tx] = f2bf(in[(long)(br + ty + i) * C + bc + tx]);
  __syncthreads();
#pragma unroll
  for (int i = 0; i < 32; i += 8)
    out[(long)(bc + ty + i) * R + br + tx] = t[tx][ty + i];
}

// ================= 256x256 8-phase GEMM (T1+T2+T3+T4+T5) =================
// C[M][N] = A[M][K] @ Bt[N][K]^T + bias[N]
// 512 threads = 8 waves (2M x 4N), per-wave output 128x64, BK=64, NT=K/64.
// LDS 128 KiB: lds[buf][mat][256*64] bf16, plain row-major [256][64],
// XOR-swizzle byte ^= (row&7)<<4 applied on the READ side; staging keeps
// the LDS dest linear and pre-swizzles the GLOBAL source (rule #21: the
// source permutation and read permutation are the same involution).
//
// Phase schedule per iteration t (K-tiles ka=2t in buf0, kb=2t+1 in buf1):
//  ph1: rd A[qm0]+B[qn0] buf0 | stage buf1-A h0 (kb)   | MFMA quad(0,0)
//  ph2: rd B[qn1] buf0        | stage buf1-A h1 (kb)   | MFMA quad(0,1)
//  ph3: rd A[qm1] buf0        | stage buf0-B h0 (2t+2) | MFMA quad(1,0)
//  ph4:                       | stage buf0-B h1; vmcnt(4) | MFMA quad(1,1)
//  ph5..ph8: same on buf1, staging buf0-A (2t+2) then buf1-B (2t+3),
//            vmcnt(4) at ph8.  vmcnt never drains to 0 in the loop (T4).
//
// vmcnt ledger (events, oldest first), verified:
//  prologue VMC4 retires buf0-{A,B}; leaves buf1-B(4).
//  ph4 VMC4 retires buf1-B, buf1-A; leaves buf0-B@kp0(4).
//  ph8 VMC4 retires buf0-B, buf0-A; leaves buf1-B@kp1(4).
// Every rd hits a buffer whose staging retired at a prior vmcnt+BAR; every
// overwrite is issued after the phase-closing BAR that follows the readers'
// own lgkmcnt(0), so no wave can clobber LDS still being read.

__device__ __forceinline__ void stg2(const ushort* src, ushort* dst, long kstride) {
  glds16(src, dst);                    // rows +0..63 of this half
  glds16(src + 64 * kstride, dst + 4096);  // rows +64..127
}

__device__ __forceinline__ void rd4(bf16x8 (&d)[4][2], const ushort* p,
                                    int kq0, int kq1) {
#pragma unroll
  for (int ii = 0; ii < 4; ii++) {
    d[ii][0] = *(const bf16x8*)&p[ii * 1024 + kq0];
    d[ii][1] = *(const bf16x8*)&p[ii * 1024 + kq1];
  }
}
__device__ __forceinline__ void rd2(bf16x8 (&d)[2][2], const ushort* p,
                                    int kq0, int kq1) {
#pragma unroll
  for (int jj = 0; jj < 2; jj++) {
    d[jj][0] = *(const bf16x8*)&p[jj * 1024 + kq0];
    d[jj][1] = *(const bf16x8*)&p[jj * 1024 + kq1];
  }
}
template <int I0, int J0>
__device__ __forceinline__ void mmq(f32x4 (&acc)[8][4], const bf16x8 (&a)[4][2],
                                    const bf16x8 (&b)[2][2]) {
#pragma unroll
  for (int ii = 0; ii < 4; ii++)
#pragma unroll
    for (int jj = 0; jj < 2; jj++)
#pragma unroll
      for (int ks = 0; ks < 2; ks++)
        acc[I0 + ii][J0 + jj] =
            mfma16(a[ii][ks], b[jj][ks], acc[I0 + ii][J0 + jj]);
}

template <bool F32OUT>
__global__ __launch_bounds__(512, 2) void gemm256(
    const ushort* __restrict__ A, const ushort* __restrict__ Bt,
    const float* __restrict__ bias, void* __restrict__ Cout,
    int N, int K, int NBM) {
  __shared__ ushort lds[2][2][16384];
  const int tid = threadIdx.x;
  const int wave = tid >> 6, lane = tid & 63;
  const int quad = lane >> 4, l16 = lane & 15;
  const int wm = wave >> 2, wn = wave & 3;   // 2 x 4 wave grid
  const long Kl = K;

  // T1: bijective XCD swizzle (grid % 8 == 0 for both call sites)
  const int nwg = gridDim.x;
  const int wg = ((int)blockIdx.x & 7) * (nwg >> 3) + ((int)blockIdx.x >> 3);
  const int bm = (wg % NBM) * 256;
  const int bn = (wg / NBM) * 256;
  const int NT = K >> 6;

  // Staging source map: LDS slot w (linear) holds element at g(w) where
  // g swaps byte bits 4-6 with the row's low bits.  Decoded per lane:
  //   row_in_64 = wave*8 + lane/8,  col16 = (lane&7) ^ (lane>>3)
  const int srow = (wave << 3) + (lane >> 3);
  const int kc8 = ((lane & 7) ^ ((lane >> 3) & 7)) << 3;
  const ushort* Asrc = A + (long)(bm + srow) * Kl + kc8;
  const ushort* Bsrc = Bt + (long)(bn + srow) * Kl + kc8;

#define STAGE(SRC, BUF, MAT, H, KT)                                       \
  stg2(SRC + (long)(H) * 128 * Kl + (long)(KT) * 64,                      \
       &lds[BUF][MAT][(H) * 8192 + (wave << 9)], Kl)

  // Read-side swizzled k-offsets: elem (r, ks*32+quad*8), group^ (r&7);
  // r&7 == l16&7 for every fragment row of this lane.
  const int kq0 = (quad ^ (l16 & 7)) << 3;
  const int kq1 = ((4 | quad) ^ (l16 & 7)) << 3;

  f32x4 acc[8][4] = {};

  // prologue: buf0 {A,B} kt=0, buf1 {B} kt=1; leave buf1-B (4 ev) in flight
  STAGE(Asrc, 0, 0, 0, 0); STAGE(Asrc, 0, 0, 1, 0);
  STAGE(Bsrc, 0, 1, 0, 0); STAGE(Bsrc, 0, 1, 1, 0);
  STAGE(Bsrc, 1, 1, 0, 1); STAGE(Bsrc, 1, 1, 1, 1);
  VMC4(); BAR();

  const int NI = NT >> 1;
#pragma unroll 1
  for (int t = 0; t < NI; ++t) {
    const int kb = 2 * t + 1;
    const int kp0 = (2 * t + 2 < NT) ? 2 * t + 2 : NT - 1;  // clamp: junk-but-safe
    const int kp1 = (2 * t + 3 < NT) ? 2 * t + 3 : NT - 1;
    bf16x8 a[4][2], b0[2][2], b1[2][2];

    // ---- ph1: buf0 quad(0,0)
    rd4(a, &lds[0][0][(wm * 128 + l16) * 64], kq0, kq1);
    rd2(b0, &lds[0][1][(wn * 64 + l16) * 64], kq0, kq1);
    STAGE(Asrc, 1, 0, 0, kb);
    BAR(); LGK0();
    PRIO1(); mmq<0, 0>(acc, a, b0); PRIO0();
    BAR();

    // ---- ph2: buf0 quad(0,1)
    rd2(b1, &lds[0][1][(wn * 64 + 32 + l16) * 64], kq0, kq1);
    STAGE(Asrc, 1, 0, 1, kb);
    BAR(); LGK0();
    PRIO1(); mmq<0, 2>(acc, a, b1); PRIO0();
    BAR();

    // ---- ph3: buf0 quad(1,0)
    rd4(a, &lds[0][0][(wm * 128 + 64 + l16) * 64], kq0, kq1);
    STAGE(Bsrc, 0, 1, 0, kp0);
    BAR(); LGK0();
    PRIO1(); mmq<4, 0>(acc, a, b0); PRIO0();
    BAR();

    // ---- ph4: buf0 quad(1,1); guard buf1 readiness
    STAGE(Bsrc, 0, 1, 1, kp0);
    VMC4();
    BAR();
    PRIO1(); mmq<4, 2>(acc, a, b1); PRIO0();
    BAR();

    // ---- ph5: buf1 quad(0,0)
    rd4(a, &lds[1][0][(wm * 128 + l16) * 64], kq0, kq1);
    rd2(b0, &lds[1][1][(wn * 64 + l16) * 64], kq0, kq1);
    STAGE(Asrc, 0, 0, 0, kp0);
    BAR(); LGK0();
    PRIO1(); mmq<0, 0>(acc, a, b0); PRIO0();
    BAR();

    // ---- ph6: buf1 quad(0,1)
    rd2(b1, &lds[1][1][(wn * 64 + 32 + l16) * 64], kq0, kq1);
    STAGE(Asrc, 0, 0, 1, kp0);
    BAR(); LGK0();
    PRIO1(); mmq<0, 2>(acc, a, b1); PRIO0();
    BAR();

    // ---- ph7: buf1 quad(1,0)
    rd4(a, &lds[1][0][(wm * 128 + 64 + l16) * 64], kq0, kq1);
    STAGE(Bsrc, 1, 1, 0, kp1);
    BAR(); LGK0();
    PRIO1(); mmq<4, 0>(acc, a, b0); PRIO0();
    BAR();

    // ---- ph8: buf1 quad(1,1); guard buf0 readiness for next iter
    STAGE(Bsrc, 1, 1, 1, kp1);
    VMC4();
    BAR();
    PRIO1(); mmq<4, 2>(acc, a, b1); PRIO0();
    BAR();
  }
  VMC0();  // drain tail prefetches before epilogue/endpgm

  // epilogue: C row = bm + wm*128 + i*16 + quad*4 + r, col = bn + wn*64 + j*16 + l16
#pragma unroll
  for (int i = 0; i < 8; i++) {
#pragma unroll
    for (int j = 0; j < 4; j++) {
      const int col = bn + wn * 64 + j * 16 + l16;
      const float bv = bias[col];
#pragma unroll
      for (int r = 0; r < 4; r++) {
        const int row = bm + wm * 128 + i * 16 + quad * 4 + r;
        const float v = acc[i][j][r] + bv;
        if (F32OUT)
          ((float*)Cout)[(long)row * N + col] = v;
        else
          ((ushort*)Cout)[(long)row * N + col] = f2bf(v);
      }
    }
  }
#undef STAGE
}

// ---------- RoPE ----------
__global__ __launch_bounds__(256) void rope_table(float* __restrict__ tab) {
  const int i = blockIdx.x * 256 + threadIdx.x;  // 2048*64
  const int d = i & 63, s = i >> 6;
  const float f = powf(10000.0f, -(float)(2 * d) / 128.0f);
  const float ang = (float)s * f;
  tab[i] = cosf(ang);
  tab[131072 + i] = sinf(ang);
}

__global__ __launch_bounds__(256) void rope_apply(ushort* __restrict__ qkv,
                                                  const float* __restrict__ tab) {
  const int idx = blockIdx.x * 256 + threadIdx.x;  // B*S*H*64 = 4194304
  const int d = idx & 63;
  const int h = (idx >> 6) & 15;
  const long bs = idx >> 10;
  const int s = (int)(bs & 2047);
  const float c = tab[(s << 6) + d];
  const float sn = tab[131072 + (s << 6) + d];
  ushort* row = qkv + bs * 6144 + h * 128;
  {
    float x1 = bf2f(row[d]), x2 = bf2f(row[d + 64]);
    row[d] = f2bf(x1 * c - x2 * sn);
    row[d + 64] = f2bf(x2 * c + x1 * sn);
  }
  {
    ushort* rk = row + 2048;
    float x1 = bf2f(rk[d]), x2 = bf2f(rk[d + 64]);
    rk[d] = f2bf(x1 * c - x2 * sn);
    rk[d + 64] = f2bf(x2 * c + x1 * sn);
  }
}

// ---------- flash attention, KV-split partial kernel ----------
// Unnormalized-exp: partial o and l over disjoint KV chunks combine by pure
// addition. Block = (qt, chunk) x (h, b); <=T iterations of 64 keys each.
// blockIdx.x enumerates (qt desc, chunk) so big blocks dispatch first.
#define KSTR 136
#define VSTR 68
__global__ __launch_bounds__(256) void attn_part(
    const ushort* __restrict__ qkv, float* __restrict__ part_o,
    float* __restrict__ part_l, int T, int slots_bh) {
  const int S = 2048, LD = 6144;
  const int tid = threadIdx.x;
  const int wave = tid >> 6, lane = tid & 63;
  const int quad = lane >> 4, l16 = lane & 15;
  const int h = blockIdx.y;
  const int b = blockIdx.z;

  // decode (qt, chunk) from blockIdx.x, qt descending
  int y = blockIdx.x, qt = -1, ch = 0;
  for (int q = 31; q >= 0; --q) {
    const int c = q / T + 1;
    if (qt < 0) {
      if (y < c) { qt = q; ch = y; } else y -= c;
    }
  }
  int sb = 0;
  for (int q = 0; q < qt; q++) sb += q / T + 1;
  const long slot = ((long)(b * 16 + h)) * slots_bh + sb + ch;

  const ushort* base = qkv + (long)b * S * LD;
  const int qrow0 = qt * 64 + wave * 16;
  const int kb0 = ch * T * 64;
  const int kbend = min((ch + 1) * T * 64, qt * 64 + 64);

  __shared__ ushort Ks[64 * KSTR];
  __shared__ ushort Vs[128 * VSTR];
  __shared__ ushort Ps[4][16 * VSTR];

  // Q fragments (A-layout)
  bf16x8 qf[4];
  {
    const ushort* qp = base + (long)(qrow0 + l16) * LD + h * 128 + quad * 8;
#pragma unroll
    for (int c = 0; c < 4; c++) qf[c] = *(const bf16x8*)(qp + c * 32);
  }

  float l_lane[4] = {0.f, 0.f, 0.f, 0.f};
  f32x4 o[8];
#pragma unroll
  for (int f = 0; f < 8; f++) o[f] = (f32x4){0.f, 0.f, 0.f, 0.f};

  const float scale = 0.08838834764831845f;  // 1/sqrt(128)

  // staging maps
  const int k_row = tid >> 4;
  const int k_dcol = (tid & 15) * 8;
  const int v_key2 = (tid & 31) * 2;
  const int v_dc0 = tid >> 5;

  for (int kb = kb0; kb < kbend; kb += 64) {
    __syncthreads();   // prior-iter LDS reads done
    // stage K [64][128]
#pragma unroll
    for (int it = 0; it < 4; it++) {
      const int row = k_row + it * 16;
      *(uint4*)&Ks[row * KSTR + k_dcol] =
          *(const uint4*)(base + (long)(kb + row) * LD + 2048 + h * 128 + k_dcol);
    }
    // stage V transposed [d][key], packed pair writes
#pragma unroll
    for (int it = 0; it < 2; it++) {
      const int dc = v_dc0 + it * 8;
      const ushort* vg = base + (long)(kb + v_key2) * LD + 4096 + h * 128 + dc * 8;
      ushort va[8] __attribute__((aligned(16)));
      ushort vb[8] __attribute__((aligned(16)));
      *(uint4*)va = *(const uint4*)vg;
      *(uint4*)vb = *(const uint4*)(vg + LD);
#pragma unroll
      for (int e = 0; e < 8; e++) {
        const uint32_t pk = (uint32_t)va[e] | ((uint32_t)vb[e] << 16);
        *(uint32_t*)&Vs[(dc * 8 + e) * VSTR + v_key2] = pk;
      }
    }
    __syncthreads();

    // wave-uniform live sub-tile count (diagonal tile only)
    int nkt = (qrow0 + 15 - kb) / 16 + 1;
    if (nkt > 4) nkt = 4;

    // S = Q K^T
    f32x4 sc[4] = {};
#pragma unroll
    for (int kt = 0; kt < 4; kt++) {
      if (kt < nkt) {
#pragma unroll
        for (int c = 0; c < 4; c++) {
          bf16x8 kf = *(const bf16x8*)&Ks[(kt * 16 + l16) * KSTR + c * 32 + quad * 8];
          sc[kt] = mfma16(qf[c], kf, sc[kt]);
        }
      }
    }

    // unnormalized exp + causal mask
#pragma unroll
    for (int r = 0; r < 4; r++) {
      const int qpos = qrow0 + quad * 4 + r;
      const int prow = (quad * 4 + r) * VSTR;
      float psum = 0.f;
#pragma unroll
      for (int kt = 0; kt < 4; kt++) {
        const float e = __expf(sc[kt][r] * scale);
        const float p = (kb + kt * 16 + l16 > qpos) ? 0.f : e;
        psum += p;
        Ps[wave][prow + kt * 16 + l16] = f2bf(p);
      }
      l_lane[r] += psum;
    }

    // PV
    bf16x8 pf0 = *(const bf16x8*)&Ps[wave][l16 * VSTR + quad * 8];
#pragma unroll
    for (int f = 0; f < 8; f++) {
      bf16x8 vf0 = *(const bf16x8*)&Vs[(f * 16 + l16) * VSTR + quad * 8];
      o[f] = mfma16(pf0, vf0, o[f]);
    }
    if (nkt > 2) {
      bf16x8 pf1 = *(const bf16x8*)&Ps[wave][l16 * VSTR + 32 + quad * 8];
#pragma unroll
      for (int f = 0; f < 8; f++) {
        bf16x8 vf1 = *(const bf16x8*)&Vs[(f * 16 + l16) * VSTR + 32 + quad * 8];
        o[f] = mfma16(pf1, vf1, o[f]);
      }
    }
  }

  // write partials: o rows are wave*16 + quad*4 + r, cols f*16+l16
  float* po = part_o + slot * 8192;
#pragma unroll
  for (int r = 0; r < 4; r++) {
    float l = l_lane[r];
    l += __shfl_xor(l, 1);
    l += __shfl_xor(l, 2);
    l += __shfl_xor(l, 4);
    l += __shfl_xor(l, 8);
    const int row = wave * 16 + quad * 4 + r;
#pragma unroll
    for (int f = 0; f < 8; f++)
      po[row * 128 + f * 16 + l16] = o[f][r];
    if (l16 == 0) part_l[slot * 64 + row] = l;
  }
}

// ---------- merge partials -> attnb (bf16) ----------
__global__ __launch_bounds__(256) void attn_merge(
    const float* __restrict__ part_o, const float* __restrict__ part_l,
    ushort* __restrict__ attnb, int T, int slots_bh) {
  const int qt = blockIdx.x, h = blockIdx.y, b = blockIdx.z;
  const int tid = threadIdx.x;
  const int cnt = qt / T + 1;
  int sb = 0;
  for (int q = 0; q < qt; q++) sb += q / T + 1;
  const long slot0 = ((long)(b * 16 + h)) * slots_bh + sb;

  for (int e4 = tid; e4 < 2048; e4 += 256) {   // float4 index within 64x128
    const int elem = e4 * 4;
    const int row = elem >> 7;
    const int d = elem & 127;
    float4 s = {0.f, 0.f, 0.f, 0.f};
    float l = 0.f;
    for (int c = 0; c < cnt; c++) {
      const float4 p = *(const float4*)&part_o[(slot0 + c) * 8192 + elem];
      s.x += p.x; s.y += p.y; s.z += p.z; s.w += p.w;
      l += part_l[(slot0 + c) * 64 + row];
    }
    const float inv = 1.0f / l;
    ushort4 ov;
    ov.x = f2bf(s.x * inv); ov.y = f2bf(s.y * inv);
    ov.z = f2bf(s.z * inv); ov.w = f2bf(s.w * inv);
    *(ushort4*)&attnb[((long)b * 2048 + qt * 64 + row) * 2048 + h * 128 + d] = ov;
  }
}

// ---------- launch ----------
static const void* find_by_size(void* const* d_in, const int* in_sizes,
                                int n_in, long want) {
  for (int i = 0; i < n_in; i++)
    if ((long)in_sizes[i] == want) return d_in[i];
  return nullptr;
}

extern "C" void kernel_launch(void* const* d_in, const int* in_sizes, int n_in,
                              void* d_out, int out_size, void* d_ws, size_t ws_size,
                              hipStream_t stream) {
  const float* hidden = (const float*)find_by_size(d_in, in_sizes, n_in, 8388608);
  const float* Wqkv   = (const float*)find_by_size(d_in, in_sizes, n_in, 12582912);
  const float* bqkv   = (const float*)find_by_size(d_in, in_sizes, n_in, 6144);
  const float* Wo     = (const float*)find_by_size(d_in, in_sizes, n_in, 4194304);
  const float* bo     = (const float*)find_by_size(d_in, in_sizes, n_in, 2048);

  uintptr_t w = (uintptr_t)d_ws;
  ushort* hiddenB = (ushort*)w; w += (size_t)4096 * 2048 * 2;
  ushort* WqkvT   = (ushort*)w; w += (size_t)6144 * 2048 * 2;
  ushort* WoT     = (ushort*)w; w += (size_t)2048 * 2048 * 2;
  ushort* qkvb    = (ushort*)w; w += (size_t)4096 * 6144 * 2;
  ushort* attnb   = (ushort*)w; w += (size_t)4096 * 2048 * 2;
  float*  tab     = (float*)w;  w += (size_t)2048 * 64 * 2 * 4;
  const size_t fixed_bytes = w - (uintptr_t)d_ws;

  // choose T (iters of 64 keys per attn block): smallest that fits ws
  int T = 8, slots_bh = 0;
  for (;; T *= 2) {
    slots_bh = 0;
    for (int q = 0; q < 32; q++) slots_bh += q / T + 1;
    const size_t need = fixed_bytes +
        (size_t)slots_bh * 32 * (8192 + 64) * 4;
    if (need <= ws_size || T >= 32) break;
  }
  float* part_o = (float*)w; w += (size_t)slots_bh * 32 * 8192 * 4;
  float* part_l = (float*)w; w += (size_t)slots_bh * 32 * 64 * 4;

  cast_f32_bf16<<<8192, 256, 0, stream>>>(hidden, hiddenB, 8388608L);
  transpose_cast<<<dim3(192, 64), 256, 0, stream>>>(Wqkv, WqkvT, 2048, 6144);
  transpose_cast<<<dim3(64, 64), 256, 0, stream>>>(Wo, WoT, 2048, 2048);
  rope_table<<<512, 256, 0, stream>>>(tab);
  // QKV: M=4096 N=6144 K=2048 -> 16x24 = 384 blocks (384%8==0)
  gemm256<false><<<dim3(384), 512, 0, stream>>>(hiddenB, WqkvT, bqkv,
                                                qkvb, 6144, 2048, 16);
  rope_apply<<<16384, 256, 0, stream>>>(qkvb, tab);
  attn_part<<<dim3(slots_bh, 16, 2), 256, 0, stream>>>(qkvb, part_o, part_l,
                                                       T, slots_bh);
  attn_merge<<<dim3(32, 16, 2), 256, 0, stream>>>(part_o, part_l, attnb,
                                                  T, slots_bh);
  // proj: M=4096 N=2048 K=2048 -> 16x8 = 128 blocks (128%8==0)
  gemm256<true><<<dim3(128), 512, 0, stream>>>(attnb, WoT, bo,
                                               d_out, 2048, 2048, 16);
}